// Round 16
// baseline (733.071 us; speedup 1.0000x reference)
//
#include <hip/hip_runtime.h>
#include <hip/hip_bf16.h>
#include <stdint.h>

typedef short short8 __attribute__((ext_vector_type(8)));
typedef short short4v __attribute__((ext_vector_type(4)));
typedef float f32x4 __attribute__((ext_vector_type(4)));
typedef float f32x16 __attribute__((ext_vector_type(16)));

#define AS1C(p) ((const __attribute__((address_space(1))) unsigned int*)(p))
#define AS3(p)  ((__attribute__((address_space(3))) unsigned int*)(p))

__device__ __forceinline__ short f2bf(float f) {
  union { float f; unsigned u; } v; v.f = f;
  unsigned r = v.u + 0x7FFFu + ((v.u >> 16) & 1u);
  return (short)(r >> 16);
}

// ---------------- cast x (f32 -> bf16), 8 elems/thread ----------------
__global__ void k_cast_bf16(const float* __restrict__ src, short* __restrict__ dst, int n8) {
  const int i = blockIdx.x * 256 + threadIdx.x;
  if (i >= n8) return;
  const float4* s = (const float4*)src + (size_t)i * 2;
  const float4 a = s[0], b = s[1];
  short8 o;
  o[0] = f2bf(a.x); o[1] = f2bf(a.y); o[2] = f2bf(a.z); o[3] = f2bf(a.w);
  o[4] = f2bf(b.x); o[5] = f2bf(b.y); o[6] = f2bf(b.z); o[7] = f2bf(b.w);
  ((short8*)dst)[i] = o;
}

// ---------------- transpose + cast: src[R][C] f32 -> dst[C][R] bf16 ----------------
__global__ void k_transpose_cast(const float* __restrict__ src, short* __restrict__ dst,
                                 int R, int C) {
  __shared__ float t[32][33];
  const int tx = threadIdx.x & 31, ty = threadIdx.x >> 5;
  const int c0 = blockIdx.x * 32, r0 = blockIdx.y * 32;
#pragma unroll
  for (int j = 0; j < 4; ++j)
    t[ty + j * 8][tx] = src[(size_t)(r0 + ty + j * 8) * C + c0 + tx];
  __syncthreads();
#pragma unroll
  for (int j = 0; j < 4; ++j)
    dst[(size_t)(c0 + ty + j * 8) * R + r0 + tx] = f2bf(t[tx][ty + j * 8]);
}

// ---------------- GEMM1: qkv = x16[order] @ wt1^T + b, fused rope, layout split ----
// R15-proven form (192 µs local optimum; 7 structural variants regressed — frozen).
__global__ __launch_bounds__(256, 2)
void k_gemm1(const short* __restrict__ x16, const short* __restrict__ wt,
             const float* __restrict__ bqkv, const int* __restrict__ order,
             const int* __restrict__ pos,
             short* __restrict__ Qp, short* __restrict__ Kp, short* __restrict__ VpT) {
  __shared__ short sA[128 * 64];
  __shared__ short sB[128 * 64];
  __shared__ int sOrd[128];

  const int tid = threadIdx.x;
  const int lane = tid & 63;
  const int wv = tid >> 6;
  const int wm = wv >> 1, wn = wv & 1;
  const int tm = blockIdx.x * 128;
  const int tn = blockIdx.y * 128;

  if (tid < 128) sOrd[tid] = order[tm + tid];
  __syncthreads();

  const char* srcA[4];
  const char* srcB[4];
  {
    const int rr = tid >> 3, ck = tid & 7;
    const int sc = (ck ^ (rr & 7)) * 16;   // pre-swizzled source chunk
#pragma unroll
    for (int is = 0; is < 4; ++is) {
      srcA[is] = (const char*)(x16 + (size_t)sOrd[is * 32 + rr] * 768) + sc;
      srcB[is] = (const char*)(wt + (size_t)(tn + is * 32 + rr) * 768) + sc;
    }
  }

  f32x4 acc[4][4] = {};
  const int ldsw = wv << 10;

  for (int kk = 0; kk < 12; ++kk) {
    const int kb = kk << 7;
#pragma unroll
    for (int is = 0; is < 4; ++is)
      __builtin_amdgcn_global_load_lds(AS1C(srcA[is] + kb), AS3((char*)sA + is * 4096 + ldsw), 16, 0, 0);
#pragma unroll
    for (int is = 0; is < 4; ++is)
      __builtin_amdgcn_global_load_lds(AS1C(srcB[is] + kb), AS3((char*)sB + is * 4096 + ldsw), 16, 0, 0);
    __syncthreads();

#pragma unroll
    for (int kbl = 0; kbl < 2; ++kbl) {
      const int ko = kbl * 64 + ((lane >> 4) << 4);
      short8 af[4], bf[4];
#pragma unroll
      for (int mi = 0; mi < 4; ++mi) {
        int row = wm * 64 + mi * 16 + (lane & 15);
        af[mi] = *(const short8*)((const char*)sA + row * 128 + (ko ^ ((row & 7) << 4)));
      }
#pragma unroll
      for (int ni = 0; ni < 4; ++ni) {
        int row = wn * 64 + ni * 16 + (lane & 15);
        bf[ni] = *(const short8*)((const char*)sB + row * 128 + (ko ^ ((row & 7) << 4)));
      }
#pragma unroll
      for (int mi = 0; mi < 4; ++mi)
#pragma unroll
        for (int ni = 0; ni < 4; ++ni)
          acc[mi][ni] = __builtin_amdgcn_mfma_f32_16x16x32_bf16(af[mi], bf[ni], acc[mi][ni], 0, 0, 0);
    }
    __syncthreads();
  }

  // ---- epilogue: bias (+rope for q/k), scatter into attention layouts ----
  const int which = tn / 768;  // block-uniform: 0=q, 1=k, 2=v
  if (which == 2) {
#pragma unroll
    for (int ni = 0; ni < 4; ++ni) {
      const int col = tn + wn * 64 + ni * 16 + (lane & 15);
      const int hcol = col - 1536;
      const int h = hcol / 48;
      const int dd = hcol % 48;
      const float bq = bqkv[col];
#pragma unroll
      for (int mi = 0; mi < 4; ++mi) {
        const int m0 = tm + wm * 64 + mi * 16 + ((lane >> 4) << 2);
        const int p = m0 >> 9, q0 = m0 & 511;
        short4v vv;
#pragma unroll
        for (int r = 0; r < 4; ++r) vv[r] = f2bf(acc[mi][ni][r] + bq);
        *(short4v*)(VpT + ((size_t)(p * 16 + h) * 48 + dd) * 512 + q0) = vv;
      }
    }
  } else {
    // inv_freq/(2pi): rope angle in REVOLUTIONS for HW v_sin/v_cos.
    const float invr = exp2f(-(float)(lane & 7) * 0.830482023721840f) * 0.15915494309189535f;
    const float qscl = 0.14433756729740644f * 1.4426950408889634f;  // scale * log2(e)
#pragma unroll
    for (int ni = 0; ni < 4; ++ni) {
      const int col = tn + wn * 64 + ni * 16 + (lane & 15);
      const int hcol = col - which * 768;
      const int h = hcol / 48;
      const int dd = hcol % 48;
      const int part = dd >> 4;   // which of the 3 rope parts (16-dim each)
      const float bq = bqkv[col];
#pragma unroll
      for (int mi = 0; mi < 4; ++mi) {
        const int m0 = tm + wm * 64 + mi * 16 + ((lane >> 4) << 2);
#pragma unroll
        for (int r = 0; r < 4; ++r) {
          const int m = m0 + r;
          float val = acc[mi][ni][r] + bq;
          const int pv = pos[m * 3 + part];
          float t = __builtin_amdgcn_fractf((float)pv * invr);
          float s, c;
          asm("v_sin_f32 %0, %1" : "=v"(s) : "v"(t));
          asm("v_cos_f32 %0, %1" : "=v"(c) : "v"(t));
          const float partner = __shfl_xor(val, 8);
          val = val * c + ((lane & 8) ? partner : -partner) * s;
          const int p = m >> 9, q = m & 511;
          const size_t ro = (size_t)(p * 16 + h) * 512 + q;
          if (which == 0) Qp[ro * 48 + dd] = f2bf(val * qscl);
          else            Kp[(ro << 6) + dd] = f2bf(val);
        }
      }
    }
  }
}

// ---------------- attention: 4-wave blocks, 256 q-rows, flash over 4 x 128 keys ----
// KVBLK=128: stage 128 keys per buffer, run the proven 64-key body twice per stage
// (hf loop; st/pk registers reused -> no VGPR growth). Barriers 9->5, drains 8->4,
// each drain covered by 2x compute. K swizzle: chunk ^= (row>>2)&7 (R14-proven).
// V: [64 d][256B rows], involution chunk ^= d&15 (2-way bank = free); pad d 48-63
// pre-zeroed, read-XOR stays within the row.
__global__ __launch_bounds__(256, 2)
void k_attn(const short* __restrict__ Qp, const short* __restrict__ Kp,
            const short* __restrict__ VpT, short* __restrict__ featp) {
  __shared__ short sK[2][128 * 64];   // 16 KB each
  __shared__ short sV[2][64 * 128];   // 16 KB each ([d][256B])

  const int tid = threadIdx.x;
  const int lane = tid & 63;
  const int wv = tid >> 6;        // 0..3
  const int l31 = lane & 31;
  const int hi = lane >> 5;
  const int bid = blockIdx.x;
  const int ph = bid >> 1;
  const int half = bid & 1;
  const int p = ph >> 4, h = ph & 15;

  // zero V pad rows (d=48..63): bytes 12288..16383 of each buffer (4 KB each)
  ((float4*)((char*)sV[0] + 12288))[tid] = make_float4(0.f, 0.f, 0.f, 0.f);
  ((float4*)((char*)sV[1] + 12288))[tid] = make_float4(0.f, 0.f, 0.f, 0.f);

  short8 qf[2][3];
  {
    const short* Qb = Qp + ((size_t)ph * 512 + half * 256 + wv * 64) * 48;
#pragma unroll
    for (int qt = 0; qt < 2; ++qt)
#pragma unroll
      for (int dk = 0; dk < 3; ++dk)
        qf[qt][dk] = *(const short8*)(Qb + (qt * 32 + l31) * 48 + dk * 16 + hi * 8);
  }

  const char* Kb = (const char*)Kp + (size_t)ph * 65536;
  const char* Vb = (const char*)VpT + (size_t)ph * 49152;
  const int ldsw = wv << 10;

  // K: LDS[o2] = G[o2 ^ ((o2>>9)&7)<<4], rows o2>>7 in 0..127 (4 chunks/thread).
  // V: LDS[o2] = G[d*1024 + ms2*256 + (o2&255)^((d&15)<<4)], d = o2>>8 (3 chunks).
  auto stage = [&](int b, int ms2) {
#pragma unroll
    for (int c = 0; c < 4; ++c) {
      const int o2 = c * 4096 + tid * 16;
      const int sw = o2 ^ ((o2 >> 5) & 0x70);
      __builtin_amdgcn_global_load_lds(AS1C(Kb + ms2 * 16384 + sw),
                                       AS3((char*)sK[b] + c * 4096 + ldsw), 16, 0, 0);
    }
#pragma unroll
    for (int c = 0; c < 3; ++c) {
      const int o2 = c * 4096 + tid * 16;
      const int d = o2 >> 8;
      const int inrow = (o2 & 255) ^ ((d & 15) << 4);
      __builtin_amdgcn_global_load_lds(AS1C(Vb + (size_t)d * 1024 + ms2 * 256 + inrow),
                                       AS3((char*)sV[b] + c * 4096 + ldsw), 16, 0, 0);
    }
  };

  stage(0, 0);
  asm volatile("s_waitcnt vmcnt(0)" ::: "memory");
  __syncthreads();

  f32x16 O[2][2] = {};
  float lr[2] = {0.f, 0.f};

  for (int ms2 = 0; ms2 < 4; ++ms2) {
    const int bb = ms2 & 1;
    if (ms2 < 3) stage(bb ^ 1, ms2 + 1);

    const char* kb = (const char*)sK[bb];
    const char* vb = (const char*)sV[bb];

#pragma unroll
    for (int hf = 0; hf < 2; ++hf) {
      // S^T = K · Q^T : D[m][q], 2 m-tiles x 2 q-tiles, K-dim = d (3 x 16)
      f32x16 st[2][2];
      {
        short8 kf[2][3];
#pragma unroll
        for (int mt = 0; mt < 2; ++mt) {
          const int row = hf * 64 + mt * 32 + l31;
          const int swr = ((row >> 2) & 7) << 4;
#pragma unroll
          for (int dk = 0; dk < 3; ++dk) {
            const int ob = (dk * 16 + hi * 8) * 2;
            kf[mt][dk] = *(const short8*)(kb + row * 128 + (ob ^ swr));
          }
        }
        __builtin_amdgcn_s_setprio(1);
#pragma unroll
        for (int mt = 0; mt < 2; ++mt)
#pragma unroll
          for (int qt = 0; qt < 2; ++qt) {
            f32x16 a = {};
#pragma unroll
            for (int dk = 0; dk < 3; ++dk)
              a = __builtin_amdgcn_mfma_f32_32x32x16_bf16(kf[mt][dk], qf[qt][dk], a, 0, 0, 0);
            st[mt][qt] = a;
          }
        __builtin_amdgcn_s_setprio(0);
      }

      // softmax: P = exp2(S) directly (Q pre-scaled; fixed-max factor cancels)
      unsigned pk[2][2][8];
#pragma unroll
      for (int qt = 0; qt < 2; ++qt) {
        float ps0 = 0.f, ps1 = 0.f;
#pragma unroll
        for (int mt = 0; mt < 2; ++mt) {
#pragma unroll
          for (int pr = 0; pr < 8; ++pr) {
            float p0 = __builtin_amdgcn_exp2f(st[mt][qt][pr * 2]);
            float p1 = __builtin_amdgcn_exp2f(st[mt][qt][pr * 2 + 1]);
            ps0 += p0; ps1 += p1;
            __hip_bfloat162 bb2 = __float22bfloat162_rn(make_float2(p0, p1));
            unsigned w; __builtin_memcpy(&w, &bb2, 4);
            pk[mt][qt][pr] = w;
          }
        }
        lr[qt] += ps0 + ps1;
      }

      // PV: A = P (half-swap redistribute via shfl_xor), B = V^T tiles of this half
      short8 vf[2][4];
#pragma unroll
      for (int dt = 0; dt < 2; ++dt) {
        const int d = dt * 32 + l31;
        const int fx = (d & 15) << 4;
#pragma unroll
        for (int ks = 0; ks < 4; ++ks) {
          const int ob = hf * 128 + (ks * 16 + hi * 8) * 2;
          vf[dt][ks] = *(const short8*)(vb + d * 256 + (ob ^ fx));
        }
      }
#pragma unroll
      for (int qt = 0; qt < 2; ++qt) {
#pragma unroll
        for (int ks = 0; ks < 4; ++ks) {
          const int mt = ks >> 1;
          const int b0 = (ks & 1) * 4;
          const unsigned X0 = pk[mt][qt][b0 + 0];
          const unsigned X1 = pk[mt][qt][b0 + 1];
          const unsigned Y0 = pk[mt][qt][b0 + 2];
          const unsigned Y1 = pk[mt][qt][b0 + 3];
          const unsigned tX0 = __shfl_xor(X0, 32);
          const unsigned tX1 = __shfl_xor(X1, 32);
          const unsigned tY0 = __shfl_xor(Y0, 32);
          const unsigned tY1 = __shfl_xor(Y1, 32);
          union { unsigned u[4]; short8 v; } aw;
          aw.u[0] = hi ? tY0 : X0;
          aw.u[1] = hi ? tY1 : X1;
          aw.u[2] = hi ? Y0 : tX0;
          aw.u[3] = hi ? Y1 : tX1;
          __builtin_amdgcn_s_setprio(1);
#pragma unroll
          for (int dt = 0; dt < 2; ++dt)
            O[qt][dt] = __builtin_amdgcn_mfma_f32_32x32x16_bf16(aw.v, vf[dt][ks], O[qt][dt], 0, 0, 0);
          __builtin_amdgcn_s_setprio(0);
        }
      }
    }

    if (ms2 < 3) {
      asm volatile("s_waitcnt vmcnt(0)" ::: "memory");
      __syncthreads();
    }
  }

  // normalize + write feat (padded layout, [tok][h*48+d] bf16)
#pragma unroll
  for (int qt = 0; qt < 2; ++qt) {
    float l = lr[qt] + __shfl_xor(lr[qt], 32);
    const float il = 1.0f / l;
#pragma unroll
    for (int r = 0; r < 16; ++r) {
      const int crow = (r & 3) + ((r >> 2) << 3) + (hi << 2);
      const float ilr = __shfl(il, crow);
      const int qg = half * 256 + wv * 64 + qt * 32 + crow;
      const size_t base = ((size_t)(p * 512 + qg)) * 768 + h * 48;
      featp[base + l31] = f2bf(O[qt][0][r] * ilr);
      if (l31 < 16) featp[base + 32 + l31] = f2bf(O[qt][1][r] * ilr);
    }
  }
}

// ---------------- GEMM2: out = featp[inverse] @ wt2^T + b_proj (f32 out) -----------
__global__ __launch_bounds__(256, 2)
void k_gemm2(const short* __restrict__ featp, const short* __restrict__ wt,
             const float* __restrict__ bproj, const int* __restrict__ inverse,
             float* __restrict__ out) {
  __shared__ short sA[128 * 64];
  __shared__ short sB[128 * 64];
  __shared__ int sInv[128];

  const int tid = threadIdx.x;
  const int lane = tid & 63;
  const int wv = tid >> 6;
  const int wm = wv >> 1, wn = wv & 1;
  const int tm = blockIdx.x * 128;
  const int tn = blockIdx.y * 128;

  if (tid < 128) sInv[tid] = inverse[tm + tid];
  __syncthreads();

  const char* srcA[4];
  const char* srcB[4];
  {
    const int rr = tid >> 3, ck = tid & 7;
    const int sc = (ck ^ (rr & 7)) * 16;
#pragma unroll
    for (int is = 0; is < 4; ++is) {
      srcA[is] = (const char*)(featp + (size_t)sInv[is * 32 + rr] * 768) + sc;
      srcB[is] = (const char*)(wt + (size_t)(tn + is * 32 + rr) * 768) + sc;
    }
  }

  f32x4 acc[4][4] = {};
  const int ldsw = wv << 10;

  for (int kk = 0; kk < 12; ++kk) {
    const int kb = kk << 7;
#pragma unroll
    for (int is = 0; is < 4; ++is)
      __builtin_amdgcn_global_load_lds(AS1C(srcA[is] + kb), AS3((char*)sA + is * 4096 + ldsw), 16, 0, 0);
#pragma unroll
    for (int is = 0; is < 4; ++is)
      __builtin_amdgcn_global_load_lds(AS1C(srcB[is] + kb), AS3((char*)sB + is * 4096 + ldsw), 16, 0, 0);
    __syncthreads();

#pragma unroll
    for (int kbl = 0; kbl < 2; ++kbl) {
      const int ko = kbl * 64 + ((lane >> 4) << 4);
      short8 af[4], bf[4];
#pragma unroll
      for (int mi = 0; mi < 4; ++mi) {
        int row = wm * 64 + mi * 16 + (lane & 15);
        af[mi] = *(const short8*)((const char*)sA + row * 128 + (ko ^ ((row & 7) << 4)));
      }
#pragma unroll
      for (int ni = 0; ni < 4; ++ni) {
        int row = wn * 64 + ni * 16 + (lane & 15);
        bf[ni] = *(const short8*)((const char*)sB + row * 128 + (ko ^ ((row & 7) << 4)));
      }
#pragma unroll
      for (int mi = 0; mi < 4; ++mi)
#pragma unroll
        for (int ni = 0; ni < 4; ++ni)
          acc[mi][ni] = __builtin_amdgcn_mfma_f32_16x16x32_bf16(af[mi], bf[ni], acc[mi][ni], 0, 0, 0);
    }
    __syncthreads();
  }

#pragma unroll
  for (int ni = 0; ni < 4; ++ni) {
    const int col = tn + wn * 64 + ni * 16 + (lane & 15);
    const float bq = bproj[col];
#pragma unroll
    for (int mi = 0; mi < 4; ++mi) {
      const int m0 = tm + wm * 64 + mi * 16 + ((lane >> 4) << 2);
#pragma unroll
      for (int r = 0; r < 4; ++r)
        out[(size_t)(m0 + r) * 768 + col] = acc[mi][ni][r] + bq;
    }
  }
}

// ---------------- launch ----------------
extern "C" void kernel_launch(void* const* d_in, const int* in_sizes, int n_in,
                              void* d_out, int out_size, void* d_ws, size_t ws_size,
                              hipStream_t stream) {
  (void)n_in; (void)out_size; (void)ws_size;
  const float* x      = (const float*)d_in[0];
  const float* w_qkv  = (const float*)d_in[1];
  const float* b_qkv  = (const float*)d_in[2];
  const float* w_proj = (const float*)d_in[3];
  const float* b_proj = (const float*)d_in[4];
  const int* order    = (const int*)d_in[5];
  const int* inverse  = (const int*)d_in[6];
  const int* pos      = (const int*)d_in[7];
  float* out = (float*)d_out;

  const int N = in_sizes[6];      // 32768
  const int Npad = in_sizes[5];   // 33792

  char* ws = (char*)d_ws;
  const size_t szTok = (size_t)Npad * 768 * 2;           // 51.9 MB
  short* x16   = (short*)ws;                              // N*768 bf16
  short* featp = (short*)ws;                              // aliases x16 (dead after gemm1)
  short* wt1 = (short*)(ws + szTok);                      // 2304x768 bf16
  short* wt2 = (short*)(ws + szTok + 3538944);            // 768x768 bf16
  short* Qp  = (short*)(ws + szTok + 3538944 + 1179648);  // ph x 512 x 48
  short* Kp  = (short*)(ws + szTok * 2 + 3538944 + 1179648);          // ph x 512 x 64
  short* VpT = (short*)(ws + szTok * 2 + 3538944 + 1179648 + (size_t)Npad * 2048); // ph x 48 x 512

  k_cast_bf16<<<dim3((N * 768 / 8 + 255) / 256), 256, 0, stream>>>(x, x16, N * 768 / 8);
  k_transpose_cast<<<dim3(2304 / 32, 768 / 32), 256, 0, stream>>>(w_qkv, wt1, 768, 2304);
  k_transpose_cast<<<dim3(768 / 32, 768 / 32), 256, 0, stream>>>(w_proj, wt2, 768, 768);
  k_gemm1<<<dim3(Npad / 128, 18), 256, 0, stream>>>(x16, wt1, b_qkv, order, pos, Qp, Kp, VpT);
  k_attn<<<dim3((Npad / 512) * 16 * 2), 256, 0, stream>>>(Qp, Kp, VpT, featp);
  k_gemm2<<<dim3(N / 128, 6), 256, 0, stream>>>(featp, wt2, b_proj, inverse, out);
}

// Round 17
// 388.817 us; speedup vs baseline: 1.8854x; 1.8854x over previous
//
#include <hip/hip_runtime.h>
#include <hip/hip_bf16.h>
#include <stdint.h>

typedef short short8 __attribute__((ext_vector_type(8)));
typedef short short4v __attribute__((ext_vector_type(4)));
typedef float f32x4 __attribute__((ext_vector_type(4)));
typedef float f32x16 __attribute__((ext_vector_type(16)));

#define AS1C(p) ((const __attribute__((address_space(1))) unsigned int*)(p))
#define AS3(p)  ((__attribute__((address_space(3))) unsigned int*)(p))

__device__ __forceinline__ short f2bf(float f) {
  union { float f; unsigned u; } v; v.f = f;
  unsigned r = v.u + 0x7FFFu + ((v.u >> 16) & 1u);
  return (short)(r >> 16);
}

// ---------------- cast x (f32 -> bf16), 8 elems/thread ----------------
__global__ void k_cast_bf16(const float* __restrict__ src, short* __restrict__ dst, int n8) {
  const int i = blockIdx.x * 256 + threadIdx.x;
  if (i >= n8) return;
  const float4* s = (const float4*)src + (size_t)i * 2;
  const float4 a = s[0], b = s[1];
  short8 o;
  o[0] = f2bf(a.x); o[1] = f2bf(a.y); o[2] = f2bf(a.z); o[3] = f2bf(a.w);
  o[4] = f2bf(b.x); o[5] = f2bf(b.y); o[6] = f2bf(b.z); o[7] = f2bf(b.w);
  ((short8*)dst)[i] = o;
}

// ---------------- transpose + cast: src[R][C] f32 -> dst[C][R] bf16 ----------------
__global__ void k_transpose_cast(const float* __restrict__ src, short* __restrict__ dst,
                                 int R, int C) {
  __shared__ float t[32][33];
  const int tx = threadIdx.x & 31, ty = threadIdx.x >> 5;
  const int c0 = blockIdx.x * 32, r0 = blockIdx.y * 32;
#pragma unroll
  for (int j = 0; j < 4; ++j)
    t[ty + j * 8][tx] = src[(size_t)(r0 + ty + j * 8) * C + c0 + tx];
  __syncthreads();
#pragma unroll
  for (int j = 0; j < 4; ++j)
    dst[(size_t)(c0 + ty + j * 8) * R + r0 + tx] = f2bf(t[tx][ty + j * 8]);
}

// ---------------- GEMM1: qkv = x16[order] @ wt1^T + b, fused rope, layout split ----
// R15-proven form (192 µs local optimum; 7 structural variants regressed — frozen).
__global__ __launch_bounds__(256, 2)
void k_gemm1(const short* __restrict__ x16, const short* __restrict__ wt,
             const float* __restrict__ bqkv, const int* __restrict__ order,
             const int* __restrict__ pos,
             short* __restrict__ Qp, short* __restrict__ Kp, short* __restrict__ VpT) {
  __shared__ short sA[128 * 64];
  __shared__ short sB[128 * 64];
  __shared__ int sOrd[128];

  const int tid = threadIdx.x;
  const int lane = tid & 63;
  const int wv = tid >> 6;
  const int wm = wv >> 1, wn = wv & 1;
  const int tm = blockIdx.x * 128;
  const int tn = blockIdx.y * 128;

  if (tid < 128) sOrd[tid] = order[tm + tid];
  __syncthreads();

  const char* srcA[4];
  const char* srcB[4];
  {
    const int rr = tid >> 3, ck = tid & 7;
    const int sc = (ck ^ (rr & 7)) * 16;   // pre-swizzled source chunk
#pragma unroll
    for (int is = 0; is < 4; ++is) {
      srcA[is] = (const char*)(x16 + (size_t)sOrd[is * 32 + rr] * 768) + sc;
      srcB[is] = (const char*)(wt + (size_t)(tn + is * 32 + rr) * 768) + sc;
    }
  }

  f32x4 acc[4][4] = {};
  const int ldsw = wv << 10;

  for (int kk = 0; kk < 12; ++kk) {
    const int kb = kk << 7;
#pragma unroll
    for (int is = 0; is < 4; ++is)
      __builtin_amdgcn_global_load_lds(AS1C(srcA[is] + kb), AS3((char*)sA + is * 4096 + ldsw), 16, 0, 0);
#pragma unroll
    for (int is = 0; is < 4; ++is)
      __builtin_amdgcn_global_load_lds(AS1C(srcB[is] + kb), AS3((char*)sB + is * 4096 + ldsw), 16, 0, 0);
    __syncthreads();

#pragma unroll
    for (int kbl = 0; kbl < 2; ++kbl) {
      const int ko = kbl * 64 + ((lane >> 4) << 4);
      short8 af[4], bf[4];
#pragma unroll
      for (int mi = 0; mi < 4; ++mi) {
        int row = wm * 64 + mi * 16 + (lane & 15);
        af[mi] = *(const short8*)((const char*)sA + row * 128 + (ko ^ ((row & 7) << 4)));
      }
#pragma unroll
      for (int ni = 0; ni < 4; ++ni) {
        int row = wn * 64 + ni * 16 + (lane & 15);
        bf[ni] = *(const short8*)((const char*)sB + row * 128 + (ko ^ ((row & 7) << 4)));
      }
#pragma unroll
      for (int mi = 0; mi < 4; ++mi)
#pragma unroll
        for (int ni = 0; ni < 4; ++ni)
          acc[mi][ni] = __builtin_amdgcn_mfma_f32_16x16x32_bf16(af[mi], bf[ni], acc[mi][ni], 0, 0, 0);
    }
    __syncthreads();
  }

  // ---- epilogue: bias (+rope for q/k), scatter into attention layouts ----
  const int which = tn / 768;  // block-uniform: 0=q, 1=k, 2=v
  if (which == 2) {
#pragma unroll
    for (int ni = 0; ni < 4; ++ni) {
      const int col = tn + wn * 64 + ni * 16 + (lane & 15);
      const int hcol = col - 1536;
      const int h = hcol / 48;
      const int dd = hcol % 48;
      const float bq = bqkv[col];
#pragma unroll
      for (int mi = 0; mi < 4; ++mi) {
        const int m0 = tm + wm * 64 + mi * 16 + ((lane >> 4) << 2);
        const int p = m0 >> 9, q0 = m0 & 511;
        short4v vv;
#pragma unroll
        for (int r = 0; r < 4; ++r) vv[r] = f2bf(acc[mi][ni][r] + bq);
        *(short4v*)(VpT + ((size_t)(p * 16 + h) * 48 + dd) * 512 + q0) = vv;
      }
    }
  } else {
    // inv_freq/(2pi): rope angle in REVOLUTIONS for HW v_sin/v_cos.
    const float invr = exp2f(-(float)(lane & 7) * 0.830482023721840f) * 0.15915494309189535f;
    const float qscl = 0.14433756729740644f * 1.4426950408889634f;  // scale * log2(e)
#pragma unroll
    for (int ni = 0; ni < 4; ++ni) {
      const int col = tn + wn * 64 + ni * 16 + (lane & 15);
      const int hcol = col - which * 768;
      const int h = hcol / 48;
      const int dd = hcol % 48;
      const int part = dd >> 4;   // which of the 3 rope parts (16-dim each)
      const float bq = bqkv[col];
#pragma unroll
      for (int mi = 0; mi < 4; ++mi) {
        const int m0 = tm + wm * 64 + mi * 16 + ((lane >> 4) << 2);
#pragma unroll
        for (int r = 0; r < 4; ++r) {
          const int m = m0 + r;
          float val = acc[mi][ni][r] + bq;
          const int pv = pos[m * 3 + part];
          float t = __builtin_amdgcn_fractf((float)pv * invr);
          float s, c;
          asm("v_sin_f32 %0, %1" : "=v"(s) : "v"(t));
          asm("v_cos_f32 %0, %1" : "=v"(c) : "v"(t));
          const float partner = __shfl_xor(val, 8);
          val = val * c + ((lane & 8) ? partner : -partner) * s;
          const int p = m >> 9, q = m & 511;
          const size_t ro = (size_t)(p * 16 + h) * 512 + q;
          if (which == 0) Qp[ro * 48 + dd] = f2bf(val * qscl);
          else            Kp[(ro << 6) + dd] = f2bf(val);
        }
      }
    }
  }
}

// ---------------- attention: 4-wave blocks, 256 q-rows each, flash over 8 x 64 keys -
// R15-proven floor configuration. Closed directions (measured): KVBLK=128 spills
// (R16, 990 MB scratch), 3 waves/SIMD spills (R8), 3-buffer counted vmcnt neutral
// (R12), conflict swizzle neutral (R14) — issue-bound at this structure.
__global__ __launch_bounds__(256, 2)
void k_attn(const short* __restrict__ Qp, const short* __restrict__ Kp,
            const short* __restrict__ VpT, short* __restrict__ featp) {
  __shared__ short sK[2][64 * 64];
  __shared__ short sV[2][64 * 64];

  const int tid = threadIdx.x;
  const int lane = tid & 63;
  const int wv = tid >> 6;        // 0..3
  const int l31 = lane & 31;
  const int hi = lane >> 5;
  const int bid = blockIdx.x;
  const int ph = bid >> 1;
  const int half = bid & 1;
  const int p = ph >> 4, h = ph & 15;

  // zero V pad rows (d=48..63) of both buffers: 2 KB each, 256 threads x 8B
  ((float2*)((char*)sV[0] + 6144))[tid] = make_float2(0.f, 0.f);
  ((float2*)((char*)sV[1] + 6144))[tid] = make_float2(0.f, 0.f);

  short8 qf[2][3];
  {
    const short* Qb = Qp + ((size_t)ph * 512 + half * 256 + wv * 64) * 48;
#pragma unroll
    for (int qt = 0; qt < 2; ++qt)
#pragma unroll
      for (int dk = 0; dk < 3; ++dk)
        qf[qt][dk] = *(const short8*)(Qb + (qt * 32 + l31) * 48 + dk * 16 + hi * 8);
  }

  const char* Kb = (const char*)Kp + (size_t)ph * 65536;
  const char* Vb = (const char*)VpT + (size_t)ph * 49152;
  const int ldsw = wv << 10;

  // staging: LDS[linear o2] = G[o2 with chunk ^= (row>>2)&7], row = o2>>7.
  auto stage = [&](int b, int ms) {
#pragma unroll
    for (int c = 0; c < 2; ++c) {
      const int o2 = c * 4096 + tid * 16;
      const int sw = o2 ^ ((o2 >> 5) & 0x70);
      __builtin_amdgcn_global_load_lds(AS1C(Kb + ms * 8192 + sw),
                                       AS3((char*)sK[b] + c * 4096 + ldsw), 16, 0, 0);
    }
    {
      const int o2 = tid * 16;
      const int d = o2 >> 7;
      const int inrow = (o2 & 127) ^ ((o2 >> 5) & 0x70);
      __builtin_amdgcn_global_load_lds(AS1C(Vb + (size_t)d * 1024 + ms * 128 + inrow),
                                       AS3((char*)sV[b] + ldsw), 16, 0, 0);
    }
    if (tid < 128) {
      const int o2 = 4096 + tid * 16;
      const int d = o2 >> 7;
      const int inrow = (o2 & 127) ^ ((o2 >> 5) & 0x70);
      __builtin_amdgcn_global_load_lds(AS1C(Vb + (size_t)d * 1024 + ms * 128 + inrow),
                                       AS3((char*)sV[b] + 4096 + ldsw), 16, 0, 0);
    }
  };

  stage(0, 0);
  asm volatile("s_waitcnt vmcnt(0)" ::: "memory");
  __syncthreads();

  f32x16 O[2][2] = {};
  float lr[2] = {0.f, 0.f};

  for (int ms = 0; ms < 8; ++ms) {
    const int bb = ms & 1;
    if (ms < 7) stage(bb ^ 1, ms + 1);

    const char* kb = (const char*)sK[bb];
    const char* vb = (const char*)sV[bb];

    // S^T = K · Q^T : D[m][q], 2 m-tiles x 2 q-tiles, K-dim = d (3 x 16)
    f32x16 st[2][2];
    {
      short8 kf[2][3];
#pragma unroll
      for (int mt = 0; mt < 2; ++mt) {
        const int row = mt * 32 + l31;
        const int swr = ((row >> 2) & 7) << 4;
#pragma unroll
        for (int dk = 0; dk < 3; ++dk) {
          const int ob = (dk * 16 + hi * 8) * 2;
          kf[mt][dk] = *(const short8*)(kb + row * 128 + (ob ^ swr));
        }
      }
      __builtin_amdgcn_s_setprio(1);
#pragma unroll
      for (int mt = 0; mt < 2; ++mt)
#pragma unroll
        for (int qt = 0; qt < 2; ++qt) {
          f32x16 a = {};
#pragma unroll
          for (int dk = 0; dk < 3; ++dk)
            a = __builtin_amdgcn_mfma_f32_32x32x16_bf16(kf[mt][dk], qf[qt][dk], a, 0, 0, 0);
          st[mt][qt] = a;
        }
      __builtin_amdgcn_s_setprio(0);
    }

    // softmax: P = exp2(S) directly (Q pre-scaled; fixed-max factor cancels)
    unsigned pk[2][2][8];
#pragma unroll
    for (int qt = 0; qt < 2; ++qt) {
      float ps0 = 0.f, ps1 = 0.f;
#pragma unroll
      for (int mt = 0; mt < 2; ++mt) {
#pragma unroll
        for (int pr = 0; pr < 8; ++pr) {
          float p0 = __builtin_amdgcn_exp2f(st[mt][qt][pr * 2]);
          float p1 = __builtin_amdgcn_exp2f(st[mt][qt][pr * 2 + 1]);
          ps0 += p0; ps1 += p1;
          __hip_bfloat162 bb2 = __float22bfloat162_rn(make_float2(p0, p1));
          unsigned w; __builtin_memcpy(&w, &bb2, 4);
          pk[mt][qt][pr] = w;
        }
      }
      lr[qt] += ps0 + ps1;
    }

    // PV: A = P (half-swap redistribute via shfl_xor, proven in R1/R3/R5), B = V^T
    short8 vf[2][4];
#pragma unroll
    for (int dt = 0; dt < 2; ++dt) {
      const int d = dt * 32 + l31;
      const int swr = ((d >> 2) & 7) << 4;
#pragma unroll
      for (int ks = 0; ks < 4; ++ks) {
        const int ob = (ks * 16 + hi * 8) * 2;
        vf[dt][ks] = *(const short8*)(vb + d * 128 + (ob ^ swr));
      }
    }
#pragma unroll
    for (int qt = 0; qt < 2; ++qt) {
#pragma unroll
      for (int ks = 0; ks < 4; ++ks) {
        const int mt = ks >> 1;
        const int b0 = (ks & 1) * 4;
        const unsigned X0 = pk[mt][qt][b0 + 0];
        const unsigned X1 = pk[mt][qt][b0 + 1];
        const unsigned Y0 = pk[mt][qt][b0 + 2];
        const unsigned Y1 = pk[mt][qt][b0 + 3];
        const unsigned tX0 = __shfl_xor(X0, 32);
        const unsigned tX1 = __shfl_xor(X1, 32);
        const unsigned tY0 = __shfl_xor(Y0, 32);
        const unsigned tY1 = __shfl_xor(Y1, 32);
        union { unsigned u[4]; short8 v; } aw;
        aw.u[0] = hi ? tY0 : X0;
        aw.u[1] = hi ? tY1 : X1;
        aw.u[2] = hi ? Y0 : tX0;
        aw.u[3] = hi ? Y1 : tX1;
        __builtin_amdgcn_s_setprio(1);
#pragma unroll
        for (int dt = 0; dt < 2; ++dt)
          O[qt][dt] = __builtin_amdgcn_mfma_f32_32x32x16_bf16(aw.v, vf[dt][ks], O[qt][dt], 0, 0, 0);
        __builtin_amdgcn_s_setprio(0);
      }
    }

    if (ms < 7) {
      asm volatile("s_waitcnt vmcnt(0)" ::: "memory");
      __syncthreads();
    }
  }

  // normalize + write feat (padded layout, [tok][h*48+d] bf16)
#pragma unroll
  for (int qt = 0; qt < 2; ++qt) {
    float l = lr[qt] + __shfl_xor(lr[qt], 32);
    const float il = 1.0f / l;
#pragma unroll
    for (int r = 0; r < 16; ++r) {
      const int crow = (r & 3) + ((r >> 2) << 3) + (hi << 2);
      const float ilr = __shfl(il, crow);
      const int qg = half * 256 + wv * 64 + qt * 32 + crow;
      const size_t base = ((size_t)(p * 512 + qg)) * 768 + h * 48;
      featp[base + l31] = f2bf(O[qt][0][r] * ilr);
      if (l31 < 16) featp[base + 32 + l31] = f2bf(O[qt][1][r] * ilr);
    }
  }
}

// ---------------- GEMM2: out = featp[inverse] @ wt2^T + b_proj (f32 out) -----------
__global__ __launch_bounds__(256, 2)
void k_gemm2(const short* __restrict__ featp, const short* __restrict__ wt,
             const float* __restrict__ bproj, const int* __restrict__ inverse,
             float* __restrict__ out) {
  __shared__ short sA[128 * 64];
  __shared__ short sB[128 * 64];
  __shared__ int sInv[128];

  const int tid = threadIdx.x;
  const int lane = tid & 63;
  const int wv = tid >> 6;
  const int wm = wv >> 1, wn = wv & 1;
  const int tm = blockIdx.x * 128;
  const int tn = blockIdx.y * 128;

  if (tid < 128) sInv[tid] = inverse[tm + tid];
  __syncthreads();

  const char* srcA[4];
  const char* srcB[4];
  {
    const int rr = tid >> 3, ck = tid & 7;
    const int sc = (ck ^ (rr & 7)) * 16;
#pragma unroll
    for (int is = 0; is < 4; ++is) {
      srcA[is] = (const char*)(featp + (size_t)sInv[is * 32 + rr] * 768) + sc;
      srcB[is] = (const char*)(wt + (size_t)(tn + is * 32 + rr) * 768) + sc;
    }
  }

  f32x4 acc[4][4] = {};
  const int ldsw = wv << 10;

  for (int kk = 0; kk < 12; ++kk) {
    const int kb = kk << 7;
#pragma unroll
    for (int is = 0; is < 4; ++is)
      __builtin_amdgcn_global_load_lds(AS1C(srcA[is] + kb), AS3((char*)sA + is * 4096 + ldsw), 16, 0, 0);
#pragma unroll
    for (int is = 0; is < 4; ++is)
      __builtin_amdgcn_global_load_lds(AS1C(srcB[is] + kb), AS3((char*)sB + is * 4096 + ldsw), 16, 0, 0);
    __syncthreads();

#pragma unroll
    for (int kbl = 0; kbl < 2; ++kbl) {
      const int ko = kbl * 64 + ((lane >> 4) << 4);
      short8 af[4], bf[4];
#pragma unroll
      for (int mi = 0; mi < 4; ++mi) {
        int row = wm * 64 + mi * 16 + (lane & 15);
        af[mi] = *(const short8*)((const char*)sA + row * 128 + (ko ^ ((row & 7) << 4)));
      }
#pragma unroll
      for (int ni = 0; ni < 4; ++ni) {
        int row = wn * 64 + ni * 16 + (lane & 15);
        bf[ni] = *(const short8*)((const char*)sB + row * 128 + (ko ^ ((row & 7) << 4)));
      }
#pragma unroll
      for (int mi = 0; mi < 4; ++mi)
#pragma unroll
        for (int ni = 0; ni < 4; ++ni)
          acc[mi][ni] = __builtin_amdgcn_mfma_f32_16x16x32_bf16(af[mi], bf[ni], acc[mi][ni], 0, 0, 0);
    }
    __syncthreads();
  }

#pragma unroll
  for (int ni = 0; ni < 4; ++ni) {
    const int col = tn + wn * 64 + ni * 16 + (lane & 15);
    const float bq = bproj[col];
#pragma unroll
    for (int mi = 0; mi < 4; ++mi) {
      const int m0 = tm + wm * 64 + mi * 16 + ((lane >> 4) << 2);
#pragma unroll
      for (int r = 0; r < 4; ++r)
        out[(size_t)(m0 + r) * 768 + col] = acc[mi][ni][r] + bq;
    }
  }
}

// ---------------- launch ----------------
extern "C" void kernel_launch(void* const* d_in, const int* in_sizes, int n_in,
                              void* d_out, int out_size, void* d_ws, size_t ws_size,
                              hipStream_t stream) {
  (void)n_in; (void)out_size; (void)ws_size;
  const float* x      = (const float*)d_in[0];
  const float* w_qkv  = (const float*)d_in[1];
  const float* b_qkv  = (const float*)d_in[2];
  const float* w_proj = (const float*)d_in[3];
  const float* b_proj = (const float*)d_in[4];
  const int* order    = (const int*)d_in[5];
  const int* inverse  = (const int*)d_in[6];
  const int* pos      = (const int*)d_in[7];
  float* out = (float*)d_out;

  const int N = in_sizes[6];      // 32768
  const int Npad = in_sizes[5];   // 33792

  char* ws = (char*)d_ws;
  const size_t szTok = (size_t)Npad * 768 * 2;           // 51.9 MB
  short* x16   = (short*)ws;                              // N*768 bf16
  short* featp = (short*)ws;                              // aliases x16 (dead after gemm1)
  short* wt1 = (short*)(ws + szTok);                      // 2304x768 bf16
  short* wt2 = (short*)(ws + szTok + 3538944);            // 768x768 bf16
  short* Qp  = (short*)(ws + szTok + 3538944 + 1179648);  // ph x 512 x 48
  short* Kp  = (short*)(ws + szTok * 2 + 3538944 + 1179648);          // ph x 512 x 64
  short* VpT = (short*)(ws + szTok * 2 + 3538944 + 1179648 + (size_t)Npad * 2048); // ph x 48 x 512

  k_cast_bf16<<<dim3((N * 768 / 8 + 255) / 256), 256, 0, stream>>>(x, x16, N * 768 / 8);
  k_transpose_cast<<<dim3(2304 / 32, 768 / 32), 256, 0, stream>>>(w_qkv, wt1, 768, 2304);
  k_transpose_cast<<<dim3(768 / 32, 768 / 32), 256, 0, stream>>>(w_proj, wt2, 768, 768);
  k_gemm1<<<dim3(Npad / 128, 18), 256, 0, stream>>>(x16, wt1, b_qkv, order, pos, Qp, Kp, VpT);
  k_attn<<<dim3((Npad / 512) * 16 * 2), 256, 0, stream>>>(Qp, Kp, VpT, featp);
  k_gemm2<<<dim3(N / 128, 6), 256, 0, stream>>>(featp, wt2, b_proj, inverse, out);
}